// Round 11
// baseline (538.395 us; speedup 1.0000x reference)
//
#include <hip/hip_runtime.h>

// BLOOM attention block on MI355X (gfx950).
// GEMMs: proven 128x128 global_load_lds structure (~838 TF) with XCD-bijective
// block chunking (T1). 8-phase 256^2 abandoned (r3/r4/r6); V-from-L2 reverted
// (r9); staging-latency fixes neutral (r7/r10) -> attn is LDS-read bound.
// Attention: 4 waves x 32 q-rows/wave (2 row-groups share every K/V LDS
// fragment read -> 2x fewer LDS reads per MFMA), single-buffer staging,
// exp2 softmax + defer-max (T13), live-guard, longest-first XCD map.

#define SEQL 2048
#define HIDN 4096
#define NHEAD 32
#define HDIM 128
#define H3 12288

typedef __bf16 bf16x8 __attribute__((ext_vector_type(8)));
typedef float f32x4 __attribute__((ext_vector_type(4)));
typedef unsigned short u16x8 __attribute__((ext_vector_type(8)));

__device__ __forceinline__ unsigned short f2bf(float f) {
  union { float f; unsigned u; } v; v.f = f;
  return (unsigned short)((v.u + 0x7FFFu + ((v.u >> 16) & 1u)) >> 16);
}

__device__ __forceinline__ void gload_lds16(const void* g, void* l) {
  __builtin_amdgcn_global_load_lds(
      (const __attribute__((address_space(1))) void*)g,
      (__attribute__((address_space(3))) void*)l, 16, 0, 0);
}

__global__ __launch_bounds__(256) void cvt_f32_bf16(
    const float* __restrict__ in, unsigned short* __restrict__ out, long long n) {
  long long i = ((long long)blockIdx.x * blockDim.x + threadIdx.x) * 8;
  long long stride = (long long)gridDim.x * blockDim.x * 8;
  for (; i < n; i += stride) {
    float4 a = *(const float4*)(in + i);
    float4 b = *(const float4*)(in + i + 4);
    u16x8 o;
    o[0] = f2bf(a.x); o[1] = f2bf(a.y); o[2] = f2bf(a.z); o[3] = f2bf(a.w);
    o[4] = f2bf(b.x); o[5] = f2bf(b.y); o[6] = f2bf(b.z); o[7] = f2bf(b.w);
    *(u16x8*)(out + i) = o;
  }
}

// C[M,N] = A[M,K] * B[N,K]^T (+ epilogue). 128x128 tile, BK=64, 4 waves,
// 16x16x32 MFMA. LDS[r][j16] = G[r][j16^(r&7)] via linear-dest gload_lds w/
// pre-swizzled source; reads XOR byte^((r&7)<<4). XCD-bijective 1-D grid.
// EPI==0: QKV scatter epilogue. EPI==1: +bias+residual, fp32 out.
template <int EPI>
__global__ __launch_bounds__(256) void gemm_nt(
    const unsigned short* __restrict__ A, const unsigned short* __restrict__ B,
    int M, int N, int K,
    const float* __restrict__ bias, const float* __restrict__ residual,
    float* __restrict__ outf,
    unsigned short* __restrict__ q_bf, unsigned short* __restrict__ k_bf,
    unsigned short* __restrict__ v_t) {
  __shared__ unsigned short As[128 * 64];
  __shared__ unsigned short Bs[128 * 64];

  const int tid = threadIdx.x;
  const int l = tid & 63;
  const int w = tid >> 6;
  const int wr = (w >> 1) * 64;
  const int wc = (w & 1) * 64;

  const int nb = gridDim.x;
  const int lin = (blockIdx.x & 7) * (nb >> 3) + (blockIdx.x >> 3);
  const int tm0 = (lin & 15) * 128;
  const int tn0 = (lin >> 4) * 128;

  const int lr = l >> 3;
  const int lc = (l & 7) ^ lr;

  f32x4 acc[4][4] = {};

  for (int kt = 0; kt < K; kt += 64) {
    __syncthreads();
#pragma unroll
    for (int i = 0; i < 4; ++i) {
      const int row = w * 32 + i * 8 + lr;
      gload_lds16(&A[(long long)(tm0 + row) * K + kt + lc * 8],
                  (char*)As + (w * 4 + i) * 1024);
      gload_lds16(&B[(long long)(tn0 + row) * K + kt + lc * 8],
                  (char*)Bs + (w * 4 + i) * 1024);
    }
    __syncthreads();
#pragma unroll
    for (int kk = 0; kk < 2; ++kk) {
      const int colb = kk * 64 + (l >> 4) * 16;
      bf16x8 af[4], bfr[4];
#pragma unroll
      for (int m = 0; m < 4; ++m) {
        int row = wr + m * 16 + (l & 15);
        af[m] = *(const bf16x8*)((char*)As + row * 128 + (colb ^ ((row & 7) << 4)));
      }
#pragma unroll
      for (int n = 0; n < 4; ++n) {
        int row = wc + n * 16 + (l & 15);
        bfr[n] = *(const bf16x8*)((char*)Bs + row * 128 + (colb ^ ((row & 7) << 4)));
      }
#pragma unroll
      for (int m = 0; m < 4; ++m)
#pragma unroll
        for (int n = 0; n < 4; ++n)
          acc[m][n] = __builtin_amdgcn_mfma_f32_16x16x32_bf16(af[m], bfr[n], acc[m][n], 0, 0, 0);
    }
  }

#pragma unroll
  for (int m = 0; m < 4; ++m) {
#pragma unroll
    for (int n = 0; n < 4; ++n) {
      const int col = tn0 + wc + n * 16 + (l & 15);
      const float bv = bias[col];
#pragma unroll
      for (int r = 0; r < 4; ++r) {
        const int rowg = tm0 + wr + m * 16 + (l >> 4) * 4 + r;
        float v = acc[m][n][r] + bv;
        if (EPI == 0) {
          const int head = col / 384;
          const int rem = col - head * 384;
          const int which = rem >> 7;
          const int d = rem & 127;
          const unsigned short bv16 = f2bf(v);
          if (which == 0)
            q_bf[(long long)(head * SEQL + rowg) * HDIM + d] = bv16;
          else if (which == 1)
            k_bf[(long long)(head * SEQL + rowg) * HDIM + d] = bv16;
          else
            v_t[(long long)(head * HDIM + d) * SEQL + rowg] = bv16;
        } else {
          const long long idx = (long long)rowg * N + col;
          outf[idx] = v + residual[idx];
        }
      }
    }
  }
}

// Flash attention, alibi + causal. 4 waves x 32 q-rows/wave (2 groups of 16),
// KV tiles of 64. Each K/V LDS fragment read feeds TWO MFMAs (one per group).
// Grid 512: xcd = b&7 owns heads [4c,4c+4); qtiles (128 rows) longest-first.
// LDS 56KB -> 2 blocks/CU.
__global__ __launch_bounds__(256) void attn_fwd(
    const unsigned short* __restrict__ q_bf, const unsigned short* __restrict__ k_bf,
    const unsigned short* __restrict__ v_t, const float* __restrict__ alibi,
    unsigned short* __restrict__ ctx_bf) {
  __shared__ unsigned short Ks[64 * 128];   // 16 KiB (rows = kv, 256B/row)
  __shared__ unsigned short Vs[128 * 64];   // 16 KiB (rows = d, 128B/row)
  __shared__ unsigned short Ps[4][32 * 64]; // 16 KiB (per-wave P, 32 rows)
  __shared__ float Al[SEQL];                // 8 KiB  (alibi*log2e)

  const int tid = threadIdx.x;
  const int l = tid & 63;
  const int w = tid >> 6;

  const float LOG2E = 1.4426950408889634f;

  // b -> (head, qtile): xcd = b&7; i_ = b>>3 in [0,64);
  // head = xcd*4 + (i_&3); qtile = 15 - (i_>>2) (longest first).
  const int b = blockIdx.x;
  const int i_ = b >> 3;
  const int h = (b & 7) * 4 + (i_ & 3);
  const int qtile = 15 - (i_ >> 2);
  const int qw = qtile * 128 + w * 32;   // this wave's 32-row base
  const int ntiles = 2 * qtile + 2;      // causal: kv through qtile*128+127

  for (int i = tid; i < ntiles * 64; i += 256) Al[i] = alibi[h * SEQL + i] * LOG2E;

  // Q fragments, 2 groups: lane l holds row qw+g*16+(l&15), cols kk*32+(l>>4)*8
  bf16x8 qf[2][4];
#pragma unroll
  for (int g = 0; g < 2; ++g) {
    const unsigned short* qp =
        &q_bf[(long long)(h * SEQL + qw + g * 16 + (l & 15)) * HDIM + (l >> 4) * 8];
#pragma unroll
    for (int kk = 0; kk < 4; ++kk) qf[g][kk] = *(const bf16x8*)(qp + kk * 32);
  }

  f32x4 oacc[2][8] = {};
  float mrun[2][4], lrun[2][4];
#pragma unroll
  for (int g = 0; g < 2; ++g)
#pragma unroll
    for (int r = 0; r < 4; ++r) { mrun[g][r] = -__builtin_inff(); lrun[g][r] = 0.f; }
  const float inv_norm2 = 0.08838834764831845f * 1.4426950408889634f;

  const int kR = l >> 4, kC = l & 15;
  const int vR = l >> 3, vC = (l & 7) ^ vR;

  for (int t = 0; t < ntiles; ++t) {
    const int kv0 = t * 64;
    __syncthreads();
    // Staging: 4 K-chunks + 4 V-chunks per wave (1KB each), 8 DMA ops.
#pragma unroll
    for (int i = 0; i < 4; ++i) {
      const int c = w * 4 + i;
      const int krow = c * 4 + kR;                 // row&7 = (i&1)*4 + kR
      const int ksrc = kC ^ ((i & 1) * 4 + kR);
      gload_lds16(&k_bf[(long long)(h * SEQL + kv0 + krow) * HDIM + ksrc * 8],
                  (char*)Ks + c * 1024);
      const int vrow = c * 8 + vR;                 // row&7 = vR
      gload_lds16(&v_t[(long long)(h * HDIM + vrow) * SEQL + kv0 + vC * 8],
                  (char*)Vs + c * 1024);
    }
    __syncthreads();

    // Wave-uniform live guard over the wave's 32 rows.
    if (kv0 <= qw + 31) {
      // QK^T: each kf read feeds both groups' MFMAs.
      f32x4 sacc[2][4] = {};
#pragma unroll
      for (int kk = 0; kk < 4; ++kk) {
        const int colb = kk * 64 + (l >> 4) * 16;
#pragma unroll
        for (int n = 0; n < 4; ++n) {
          const int row = n * 16 + (l & 15);
          bf16x8 kf = *(const bf16x8*)((char*)Ks + row * 256 +
                                       (colb ^ ((row & 7) << 4)));
          sacc[0][n] = __builtin_amdgcn_mfma_f32_16x16x32_bf16(qf[0][kk], kf, sacc[0][n], 0, 0, 0);
          sacc[1][n] = __builtin_amdgcn_mfma_f32_16x16x32_bf16(qf[1][kk], kf, sacc[1][n], 0, 0, 0);
        }
      }

      // Per-group: mask + online softmax (exp2, defer-max) + P write.
#pragma unroll
      for (int g = 0; g < 2; ++g) {
        const int qwg = qw + g * 16;
        float sc[4][4];
#pragma unroll
        for (int n = 0; n < 4; ++n) {
          const int kv = kv0 + n * 16 + (l & 15);
          const float al = Al[kv];
#pragma unroll
          for (int r = 0; r < 4; ++r) {
            const int qrow = qwg + (l >> 4) * 4 + r;
            float v = al + inv_norm2 * sacc[g][n][r];
            sc[n][r] = (kv > qrow) ? -__builtin_inff() : v;
          }
        }
#pragma unroll
        for (int r = 0; r < 4; ++r) {
          float m0 = fmaxf(fmaxf(sc[0][r], sc[1][r]), fmaxf(sc[2][r], sc[3][r]));
          m0 = fmaxf(m0, __shfl_xor(m0, 1, 64));
          m0 = fmaxf(m0, __shfl_xor(m0, 2, 64));
          m0 = fmaxf(m0, __shfl_xor(m0, 4, 64));
          m0 = fmaxf(m0, __shfl_xor(m0, 8, 64));
          if (__ballot(m0 > mrun[g][r] + 11.0f)) {
            const float mnew = fmaxf(mrun[g][r], m0);
            const float scale = exp2f(mrun[g][r] - mnew);
            mrun[g][r] = mnew;
            lrun[g][r] *= scale;
#pragma unroll
            for (int n2 = 0; n2 < 8; ++n2) oacc[g][n2][r] *= scale;
          }
          float p0 = 0.f;
#pragma unroll
          for (int n = 0; n < 4; ++n) {
            const float pv = exp2f(sc[n][r] - mrun[g][r]);
            sc[n][r] = pv;
            p0 += pv;
          }
          p0 += __shfl_xor(p0, 1, 64);
          p0 += __shfl_xor(p0, 2, 64);
          p0 += __shfl_xor(p0, 4, 64);
          p0 += __shfl_xor(p0, 8, 64);
          lrun[g][r] += p0;
        }
        // P -> per-wave LDS rows [g*16, g*16+16)
#pragma unroll
        for (int n = 0; n < 4; ++n)
#pragma unroll
          for (int r = 0; r < 4; ++r) {
            const int row = g * 16 + (l >> 4) * 4 + r;
            const int colp = n * 16 + (l & 15);
            *(unsigned short*)((char*)Ps[w] + row * 128 +
                               ((colp * 2) ^ ((row & 7) << 4))) = f2bf(sc[n][r]);
          }
      }
      __threadfence_block();

      bf16x8 pf[2][2];
#pragma unroll
      for (int g = 0; g < 2; ++g)
#pragma unroll
        for (int kk2 = 0; kk2 < 2; ++kk2) {
          const int row = g * 16 + (l & 15);
          const int colb = kk2 * 64 + (l >> 4) * 16;
          pf[g][kk2] = *(const bf16x8*)((char*)Ps[w] + row * 128 +
                                        (colb ^ ((row & 7) << 4)));
        }

      // PV: each vf read feeds both groups' MFMAs.
#pragma unroll
      for (int n2 = 0; n2 < 8; ++n2) {
#pragma unroll
        for (int kk2 = 0; kk2 < 2; ++kk2) {
          const int row = n2 * 16 + (l & 15);
          const int colb = kk2 * 64 + (l >> 4) * 16;
          bf16x8 vf = *(const bf16x8*)((char*)Vs + row * 128 +
                                       (colb ^ ((row & 7) << 4)));
          oacc[0][n2] = __builtin_amdgcn_mfma_f32_16x16x32_bf16(pf[0][kk2], vf, oacc[0][n2], 0, 0, 0);
          oacc[1][n2] = __builtin_amdgcn_mfma_f32_16x16x32_bf16(pf[1][kk2], vf, oacc[1][n2], 0, 0, 0);
        }
      }
    }
  }

  // write ctx as bf16 [s][H], col = h*128 + d
#pragma unroll
  for (int g = 0; g < 2; ++g)
#pragma unroll
    for (int n2 = 0; n2 < 8; ++n2)
#pragma unroll
      for (int r = 0; r < 4; ++r) {
        const int qrow = qw + g * 16 + (l >> 4) * 4 + r;
        const int col = h * HDIM + n2 * 16 + (l & 15);
        ctx_bf[(long long)qrow * HIDN + col] = f2bf(oacc[g][n2][r] / lrun[g][r]);
      }
}

extern "C" void kernel_launch(void* const* d_in, const int* in_sizes, int n_in,
                              void* d_out, int out_size, void* d_ws, size_t ws_size,
                              hipStream_t stream) {
  const float* hidden = (const float*)d_in[0];
  const float* residual = (const float*)d_in[1];
  const float* alibi = (const float*)d_in[2];
  // d_in[3]: attention_mask (bool) — causal mask computed analytically
  const float* Wqkv = (const float*)d_in[4];
  const float* bqkv = (const float*)d_in[5];
  const float* Wd = (const float*)d_in[6];
  const float* bd = (const float*)d_in[7];
  float* out = (float*)d_out;

  char* ws = (char*)d_ws;
  const size_t MB16 = 16777216;
  unsigned short* q_bf = (unsigned short*)(ws);
  unsigned short* k_bf = (unsigned short*)(ws + MB16);
  unsigned short* v_t = (unsigned short*)(ws + 2 * MB16);
  unsigned short* hid_bf = (unsigned short*)(ws + 3 * MB16);
  unsigned short* wqkv_bf = (unsigned short*)(ws + 4 * MB16);  // 96 MiB
  unsigned short* wd_bf = (unsigned short*)(ws + 4 * MB16);    // reuse after QKV GEMM
  unsigned short* ctx_bf = (unsigned short*)(ws + 4 * MB16 + 33554432);

  // 1. convert inputs to bf16
  cvt_f32_bf16<<<4096, 256, 0, stream>>>(hidden, hid_bf, (long long)SEQL * HIDN);
  cvt_f32_bf16<<<24576, 256, 0, stream>>>(Wqkv, wqkv_bf, (long long)H3 * HIDN);

  // 2. QKV projection (128^2, XCD-chunked) with interleaved-scatter epilogue
  gemm_nt<0><<<(SEQL / 128) * (H3 / 128), 256, 0, stream>>>(
      hid_bf, wqkv_bf, SEQL, H3, HIDN, bqkv, nullptr, nullptr, q_bf, k_bf, v_t);

  // 3. convert Wd (reuses Wqkv region — stream-ordered after QKV GEMM)
  cvt_f32_bf16<<<8192, 256, 0, stream>>>(Wd, wd_bf, (long long)HIDN * HIDN);

  // 4. flash attention: 4 waves x 32 q-rows (2 groups share K/V LDS reads)
  attn_fwd<<<NHEAD * (SEQL / 128), 256, 0, stream>>>(q_bf, k_bf, v_t, alibi, ctx_bf);

  // 5. output projection + bias + residual (fp32 out)
  gemm_nt<1><<<(SEQL / 128) * (HIDN / 128), 256, 0, stream>>>(
      ctx_bf, wd_bf, SEQL, HIDN, HIDN, bd, residual, out, nullptr, nullptr, nullptr);
}

// Round 12
// 503.623 us; speedup vs baseline: 1.0690x; 1.0690x over previous
//
#include <hip/hip_runtime.h>

// BLOOM attention block on MI355X (gfx950). BEST-KNOWN CONFIG (round-7 state).
// GEMMs: proven 128x128 global_load_lds structure (~838 TF, 92% of the
// m97-structure ceiling) with XCD-bijective block chunking (T1).
// Attention: flash w/ alibi+causal, 4 waves x 64 q-rows, single-buffer K/V
// staging, exp2-domain softmax + defer-max (T13), longest-first XCD map.
// Abandoned after measured regressions: 256^2 8-phase QKV (r3/r4/r6),
// V-direct-from-L2 (r9), attn dbuf+counted-vmcnt (r10, neutral),
// 2-row-group read sharing (r11). This config: 497-507us across 3 runs.

#define SEQL 2048
#define HIDN 4096
#define NHEAD 32
#define HDIM 128
#define H3 12288

typedef __bf16 bf16x8 __attribute__((ext_vector_type(8)));
typedef float f32x4 __attribute__((ext_vector_type(4)));
typedef unsigned short u16x8 __attribute__((ext_vector_type(8)));

__device__ __forceinline__ unsigned short f2bf(float f) {
  union { float f; unsigned u; } v; v.f = f;
  return (unsigned short)((v.u + 0x7FFFu + ((v.u >> 16) & 1u)) >> 16);
}

__device__ __forceinline__ void gload_lds16(const void* g, void* l) {
  __builtin_amdgcn_global_load_lds(
      (const __attribute__((address_space(1))) void*)g,
      (__attribute__((address_space(3))) void*)l, 16, 0, 0);
}

__global__ __launch_bounds__(256) void cvt_f32_bf16(
    const float* __restrict__ in, unsigned short* __restrict__ out, long long n) {
  long long i = ((long long)blockIdx.x * blockDim.x + threadIdx.x) * 8;
  long long stride = (long long)gridDim.x * blockDim.x * 8;
  for (; i < n; i += stride) {
    float4 a = *(const float4*)(in + i);
    float4 b = *(const float4*)(in + i + 4);
    u16x8 o;
    o[0] = f2bf(a.x); o[1] = f2bf(a.y); o[2] = f2bf(a.z); o[3] = f2bf(a.w);
    o[4] = f2bf(b.x); o[5] = f2bf(b.y); o[6] = f2bf(b.z); o[7] = f2bf(b.w);
    *(u16x8*)(out + i) = o;
  }
}

// C[M,N] = A[M,K] * B[N,K]^T (+ epilogue). 128x128 tile, BK=64, 4 waves,
// 16x16x32 MFMA. LDS[r][j16] = G[r][j16^(r&7)] via linear-dest gload_lds w/
// pre-swizzled source; reads XOR byte^((r&7)<<4). XCD-bijective 1-D grid.
// EPI==0: QKV scatter epilogue. EPI==1: +bias+residual, fp32 out.
template <int EPI>
__global__ __launch_bounds__(256) void gemm_nt(
    const unsigned short* __restrict__ A, const unsigned short* __restrict__ B,
    int M, int N, int K,
    const float* __restrict__ bias, const float* __restrict__ residual,
    float* __restrict__ outf,
    unsigned short* __restrict__ q_bf, unsigned short* __restrict__ k_bf,
    unsigned short* __restrict__ v_t) {
  __shared__ unsigned short As[128 * 64];
  __shared__ unsigned short Bs[128 * 64];

  const int tid = threadIdx.x;
  const int l = tid & 63;
  const int w = tid >> 6;
  const int wr = (w >> 1) * 64;
  const int wc = (w & 1) * 64;

  const int nb = gridDim.x;
  const int lin = (blockIdx.x & 7) * (nb >> 3) + (blockIdx.x >> 3);
  const int tm0 = (lin & 15) * 128;
  const int tn0 = (lin >> 4) * 128;

  const int lr = l >> 3;
  const int lc = (l & 7) ^ lr;

  f32x4 acc[4][4] = {};

  for (int kt = 0; kt < K; kt += 64) {
    __syncthreads();
#pragma unroll
    for (int i = 0; i < 4; ++i) {
      const int row = w * 32 + i * 8 + lr;
      gload_lds16(&A[(long long)(tm0 + row) * K + kt + lc * 8],
                  (char*)As + (w * 4 + i) * 1024);
      gload_lds16(&B[(long long)(tn0 + row) * K + kt + lc * 8],
                  (char*)Bs + (w * 4 + i) * 1024);
    }
    __syncthreads();
#pragma unroll
    for (int kk = 0; kk < 2; ++kk) {
      const int colb = kk * 64 + (l >> 4) * 16;
      bf16x8 af[4], bfr[4];
#pragma unroll
      for (int m = 0; m < 4; ++m) {
        int row = wr + m * 16 + (l & 15);
        af[m] = *(const bf16x8*)((char*)As + row * 128 + (colb ^ ((row & 7) << 4)));
      }
#pragma unroll
      for (int n = 0; n < 4; ++n) {
        int row = wc + n * 16 + (l & 15);
        bfr[n] = *(const bf16x8*)((char*)Bs + row * 128 + (colb ^ ((row & 7) << 4)));
      }
#pragma unroll
      for (int m = 0; m < 4; ++m)
#pragma unroll
        for (int n = 0; n < 4; ++n)
          acc[m][n] = __builtin_amdgcn_mfma_f32_16x16x32_bf16(af[m], bfr[n], acc[m][n], 0, 0, 0);
    }
  }

#pragma unroll
  for (int m = 0; m < 4; ++m) {
#pragma unroll
    for (int n = 0; n < 4; ++n) {
      const int col = tn0 + wc + n * 16 + (l & 15);
      const float bv = bias[col];
#pragma unroll
      for (int r = 0; r < 4; ++r) {
        const int rowg = tm0 + wr + m * 16 + (l >> 4) * 4 + r;
        float v = acc[m][n][r] + bv;
        if (EPI == 0) {
          const int head = col / 384;
          const int rem = col - head * 384;
          const int which = rem >> 7;
          const int d = rem & 127;
          const unsigned short bv16 = f2bf(v);
          if (which == 0)
            q_bf[(long long)(head * SEQL + rowg) * HDIM + d] = bv16;
          else if (which == 1)
            k_bf[(long long)(head * SEQL + rowg) * HDIM + d] = bv16;
          else
            v_t[(long long)(head * HDIM + d) * SEQL + rowg] = bv16;
        } else {
          const long long idx = (long long)rowg * N + col;
          outf[idx] = v + residual[idx];
        }
      }
    }
  }
}

// Flash attention with alibi + causal mask. exp2-domain softmax + defer-max.
// 1-D grid of 1024 blocks. XCD c = b&7 owns heads [4c,4c+4);
// q-tiles dispatched longest-first within each XCD for tail packing.
// Block: one head x 64 q rows. 4 waves, each owns 16 q rows. KV tiles of 64.
__global__ __launch_bounds__(256) void attn_fwd(
    const unsigned short* __restrict__ q_bf, const unsigned short* __restrict__ k_bf,
    const unsigned short* __restrict__ v_t, const float* __restrict__ alibi,
    unsigned short* __restrict__ ctx_bf) {
  __shared__ unsigned short Ks[64 * 128];   // 16 KiB (rows = kv, 256B/row)
  __shared__ unsigned short Vs[128 * 64];   // 16 KiB (rows = d, 128B/row)
  __shared__ unsigned short Ps[4][16 * 64]; // 8 KiB  (per-wave P tile)
  __shared__ float Al[SEQL];                // 8 KiB  (alibi*log2e)

  const int tid = threadIdx.x;
  const int l = tid & 63;
  const int w = tid >> 6;

  const float LOG2E = 1.4426950408889634f;

  const int b = blockIdx.x;
  const int i_ = b >> 3;
  const int h = (b & 7) * 4 + (i_ & 3);
  const int qtile = 31 - (i_ >> 2);
  const int qw = qtile * 64 + w * 16;

  for (int i = tid; i < SEQL; i += 256) Al[i] = alibi[h * SEQL + i] * LOG2E;

  bf16x8 qf[4];
  {
    const unsigned short* qp =
        &q_bf[(long long)(h * SEQL + qw + (l & 15)) * HDIM + (l >> 4) * 8];
#pragma unroll
    for (int kk = 0; kk < 4; ++kk) qf[kk] = *(const bf16x8*)(qp + kk * 32);
  }

  f32x4 oacc[8] = {};
  float mrun[4] = {-__builtin_inff(), -__builtin_inff(), -__builtin_inff(), -__builtin_inff()};
  float lrun[4] = {0.f, 0.f, 0.f, 0.f};
  const float inv_norm2 = 0.08838834764831845f * 1.4426950408889634f;

  const int kR = l >> 4, kC = l & 15;
  const int vR = l >> 3, vC = (l & 7) ^ vR;

  const int ntiles = qtile + 1;
  for (int t = 0; t < ntiles; ++t) {
    const int kv0 = t * 64;
    __syncthreads();
#pragma unroll
    for (int i = 0; i < 4; ++i) {
      const int krow = w * 16 + i * 4 + kR;
      const int ksrc = kC ^ ((i & 1) * 4 + kR);
      gload_lds16(&k_bf[(long long)(h * SEQL + kv0 + krow) * HDIM + ksrc * 8],
                  (char*)Ks + (w * 4 + i) * 1024);
      const int vrow = w * 32 + i * 8 + vR;
      gload_lds16(&v_t[(long long)(h * HDIM + vrow) * SEQL + kv0 + vC * 8],
                  (char*)Vs + (w * 4 + i) * 1024);
    }
    __syncthreads();

    f32x4 sacc[4] = {};
#pragma unroll
    for (int kk = 0; kk < 4; ++kk) {
      const int colb = kk * 64 + (l >> 4) * 16;
#pragma unroll
      for (int n = 0; n < 4; ++n) {
        int row = n * 16 + (l & 15);
        bf16x8 kf = *(const bf16x8*)((char*)Ks + row * 256 + (colb ^ ((row & 7) << 4)));
        sacc[n] = __builtin_amdgcn_mfma_f32_16x16x32_bf16(qf[kk], kf, sacc[n], 0, 0, 0);
      }
    }

    float sc[4][4];
#pragma unroll
    for (int n = 0; n < 4; ++n) {
      const int kv = kv0 + n * 16 + (l & 15);
      const float al = Al[kv];
#pragma unroll
      for (int r = 0; r < 4; ++r) {
        const int qrow = qw + (l >> 4) * 4 + r;
        float v = al + inv_norm2 * sacc[n][r];
        sc[n][r] = (kv > qrow) ? -__builtin_inff() : v;
      }
    }

#pragma unroll
    for (int r = 0; r < 4; ++r) {
      float m0 = fmaxf(fmaxf(sc[0][r], sc[1][r]), fmaxf(sc[2][r], sc[3][r]));
      m0 = fmaxf(m0, __shfl_xor(m0, 1, 64));
      m0 = fmaxf(m0, __shfl_xor(m0, 2, 64));
      m0 = fmaxf(m0, __shfl_xor(m0, 4, 64));
      m0 = fmaxf(m0, __shfl_xor(m0, 8, 64));
      if (__ballot(m0 > mrun[r] + 11.0f)) {
        const float mnew = fmaxf(mrun[r], m0);
        const float scale = exp2f(mrun[r] - mnew);
        mrun[r] = mnew;
        lrun[r] *= scale;
#pragma unroll
        for (int n2 = 0; n2 < 8; ++n2) oacc[n2][r] *= scale;
      }
      float p0 = 0.f;
#pragma unroll
      for (int n = 0; n < 4; ++n) {
        const float pv = exp2f(sc[n][r] - mrun[r]);
        sc[n][r] = pv;
        p0 += pv;
      }
      p0 += __shfl_xor(p0, 1, 64);
      p0 += __shfl_xor(p0, 2, 64);
      p0 += __shfl_xor(p0, 4, 64);
      p0 += __shfl_xor(p0, 8, 64);
      lrun[r] += p0;
    }

#pragma unroll
    for (int n = 0; n < 4; ++n)
#pragma unroll
      for (int r = 0; r < 4; ++r) {
        const int row = (l >> 4) * 4 + r;
        const int colp = n * 16 + (l & 15);
        *(unsigned short*)((char*)Ps[w] + row * 128 + ((colp * 2) ^ ((row & 7) << 4))) =
            f2bf(sc[n][r]);
      }
    __threadfence_block();
    bf16x8 pf[2];
#pragma unroll
    for (int kk2 = 0; kk2 < 2; ++kk2) {
      const int row = l & 15;
      const int colb = kk2 * 64 + (l >> 4) * 16;
      pf[kk2] = *(const bf16x8*)((char*)Ps[w] + row * 128 + (colb ^ ((row & 7) << 4)));
    }

#pragma unroll
    for (int n2 = 0; n2 < 8; ++n2) {
#pragma unroll
      for (int kk2 = 0; kk2 < 2; ++kk2) {
        const int row = n2 * 16 + (l & 15);
        const int colb = kk2 * 64 + (l >> 4) * 16;
        bf16x8 vf = *(const bf16x8*)((char*)Vs + row * 128 + (colb ^ ((row & 7) << 4)));
        oacc[n2] = __builtin_amdgcn_mfma_f32_16x16x32_bf16(pf[kk2], vf, oacc[n2], 0, 0, 0);
      }
    }
  }

#pragma unroll
  for (int n2 = 0; n2 < 8; ++n2)
#pragma unroll
    for (int r = 0; r < 4; ++r) {
      const int qrow = qw + (l >> 4) * 4 + r;
      const int col = h * HDIM + n2 * 16 + (l & 15);
      ctx_bf[(long long)qrow * HIDN + col] = f2bf(oacc[n2][r] / lrun[r]);
    }
}

extern "C" void kernel_launch(void* const* d_in, const int* in_sizes, int n_in,
                              void* d_out, int out_size, void* d_ws, size_t ws_size,
                              hipStream_t stream) {
  const float* hidden = (const float*)d_in[0];
  const float* residual = (const float*)d_in[1];
  const float* alibi = (const float*)d_in[2];
  // d_in[3]: attention_mask (bool) — causal mask computed analytically
  const float* Wqkv = (const float*)d_in[4];
  const float* bqkv = (const float*)d_in[5];
  const float* Wd = (const float*)d_in[6];
  const float* bd = (const float*)d_in[7];
  float* out = (float*)d_out;

  char* ws = (char*)d_ws;
  const size_t MB16 = 16777216;
  unsigned short* q_bf = (unsigned short*)(ws);
  unsigned short* k_bf = (unsigned short*)(ws + MB16);
  unsigned short* v_t = (unsigned short*)(ws + 2 * MB16);
  unsigned short* hid_bf = (unsigned short*)(ws + 3 * MB16);
  unsigned short* wqkv_bf = (unsigned short*)(ws + 4 * MB16);  // 96 MiB
  unsigned short* wd_bf = (unsigned short*)(ws + 4 * MB16);    // reuse after QKV GEMM
  unsigned short* ctx_bf = (unsigned short*)(ws + 4 * MB16 + 33554432);

  // 1. convert inputs to bf16
  cvt_f32_bf16<<<4096, 256, 0, stream>>>(hidden, hid_bf, (long long)SEQL * HIDN);
  cvt_f32_bf16<<<24576, 256, 0, stream>>>(Wqkv, wqkv_bf, (long long)H3 * HIDN);

  // 2. QKV projection (128^2, XCD-chunked) with interleaved-scatter epilogue
  gemm_nt<0><<<(SEQL / 128) * (H3 / 128), 256, 0, stream>>>(
      hid_bf, wqkv_bf, SEQL, H3, HIDN, bqkv, nullptr, nullptr, q_bf, k_bf, v_t);

  // 3. convert Wd (reuses Wqkv region — stream-ordered after QKV GEMM)
  cvt_f32_bf16<<<8192, 256, 0, stream>>>(Wd, wd_bf, (long long)HIDN * HIDN);

  // 4. flash attention (alibi + causal), longest-first + XCD head-chunking
  attn_fwd<<<NHEAD * (SEQL / 64), 256, 0, stream>>>(q_bf, k_bf, v_t, alibi, ctx_bf);

  // 5. output projection + bias + residual (fp32 out)
  gemm_nt<1><<<(SEQL / 128) * (HIDN / 128), 256, 0, stream>>>(
      ctx_bf, wd_bf, SEQL, HIDN, HIDN, bd, residual, out, nullptr, nullptr, nullptr);
}

// Round 13
// 474.814 us; speedup vs baseline: 1.1339x; 1.0607x over previous
//
#include <hip/hip_runtime.h>

// BLOOM attention block on MI355X (gfx950).
// GEMMs: proven 128x128 global_load_lds structure (~838 TF) with XCD-bijective
// block chunking (T1). [unchanged from the best-known r12 config]
// Attention: flash w/ alibi+causal, 4 waves x 64 q-rows, SWAPPED-OPERAND QK^T
// -> in-register softmax (lane owns one q-row: local reduce + 2 shfl), P
// repacked to the PV B-operand via v_cvt_pk_bf16_f32 + lane shuffles (no P
// LDS round-trip), O^T transposed once through reused LDS at the end.
// exp2-domain softmax + defer-max (T13), live-guard, longest-first XCD map.

#define SEQL 2048
#define HIDN 4096
#define NHEAD 32
#define HDIM 128
#define H3 12288

typedef __bf16 bf16x8 __attribute__((ext_vector_type(8)));
typedef float f32x4 __attribute__((ext_vector_type(4)));
typedef unsigned short u16x8 __attribute__((ext_vector_type(8)));
typedef unsigned int u32x4 __attribute__((ext_vector_type(4)));

__device__ __forceinline__ unsigned short f2bf(float f) {
  union { float f; unsigned u; } v; v.f = f;
  return (unsigned short)((v.u + 0x7FFFu + ((v.u >> 16) & 1u)) >> 16);
}

__device__ __forceinline__ unsigned cvtpk(float lo, float hi) {
  unsigned r;
  asm("v_cvt_pk_bf16_f32 %0, %1, %2" : "=v"(r) : "v"(lo), "v"(hi));
  return r;
}

__device__ __forceinline__ void gload_lds16(const void* g, void* l) {
  __builtin_amdgcn_global_load_lds(
      (const __attribute__((address_space(1))) void*)g,
      (__attribute__((address_space(3))) void*)l, 16, 0, 0);
}

__global__ __launch_bounds__(256) void cvt_f32_bf16(
    const float* __restrict__ in, unsigned short* __restrict__ out, long long n) {
  long long i = ((long long)blockIdx.x * blockDim.x + threadIdx.x) * 8;
  long long stride = (long long)gridDim.x * blockDim.x * 8;
  for (; i < n; i += stride) {
    float4 a = *(const float4*)(in + i);
    float4 b = *(const float4*)(in + i + 4);
    u16x8 o;
    o[0] = f2bf(a.x); o[1] = f2bf(a.y); o[2] = f2bf(a.z); o[3] = f2bf(a.w);
    o[4] = f2bf(b.x); o[5] = f2bf(b.y); o[6] = f2bf(b.z); o[7] = f2bf(b.w);
    *(u16x8*)(out + i) = o;
  }
}

// C[M,N] = A[M,K] * B[N,K]^T (+ epilogue). 128x128 tile, BK=64, 4 waves,
// 16x16x32 MFMA. LDS[r][j16] = G[r][j16^(r&7)] via linear-dest gload_lds w/
// pre-swizzled source; reads XOR byte^((r&7)<<4). XCD-bijective 1-D grid.
// EPI==0: QKV scatter epilogue. EPI==1: +bias+residual, fp32 out.
template <int EPI>
__global__ __launch_bounds__(256) void gemm_nt(
    const unsigned short* __restrict__ A, const unsigned short* __restrict__ B,
    int M, int N, int K,
    const float* __restrict__ bias, const float* __restrict__ residual,
    float* __restrict__ outf,
    unsigned short* __restrict__ q_bf, unsigned short* __restrict__ k_bf,
    unsigned short* __restrict__ v_t) {
  __shared__ unsigned short As[128 * 64];
  __shared__ unsigned short Bs[128 * 64];

  const int tid = threadIdx.x;
  const int l = tid & 63;
  const int w = tid >> 6;
  const int wr = (w >> 1) * 64;
  const int wc = (w & 1) * 64;

  const int nb = gridDim.x;
  const int lin = (blockIdx.x & 7) * (nb >> 3) + (blockIdx.x >> 3);
  const int tm0 = (lin & 15) * 128;
  const int tn0 = (lin >> 4) * 128;

  const int lr = l >> 3;
  const int lc = (l & 7) ^ lr;

  f32x4 acc[4][4] = {};

  for (int kt = 0; kt < K; kt += 64) {
    __syncthreads();
#pragma unroll
    for (int i = 0; i < 4; ++i) {
      const int row = w * 32 + i * 8 + lr;
      gload_lds16(&A[(long long)(tm0 + row) * K + kt + lc * 8],
                  (char*)As + (w * 4 + i) * 1024);
      gload_lds16(&B[(long long)(tn0 + row) * K + kt + lc * 8],
                  (char*)Bs + (w * 4 + i) * 1024);
    }
    __syncthreads();
#pragma unroll
    for (int kk = 0; kk < 2; ++kk) {
      const int colb = kk * 64 + (l >> 4) * 16;
      bf16x8 af[4], bfr[4];
#pragma unroll
      for (int m = 0; m < 4; ++m) {
        int row = wr + m * 16 + (l & 15);
        af[m] = *(const bf16x8*)((char*)As + row * 128 + (colb ^ ((row & 7) << 4)));
      }
#pragma unroll
      for (int n = 0; n < 4; ++n) {
        int row = wc + n * 16 + (l & 15);
        bfr[n] = *(const bf16x8*)((char*)Bs + row * 128 + (colb ^ ((row & 7) << 4)));
      }
#pragma unroll
      for (int m = 0; m < 4; ++m)
#pragma unroll
        for (int n = 0; n < 4; ++n)
          acc[m][n] = __builtin_amdgcn_mfma_f32_16x16x32_bf16(af[m], bfr[n], acc[m][n], 0, 0, 0);
    }
  }

#pragma unroll
  for (int m = 0; m < 4; ++m) {
#pragma unroll
    for (int n = 0; n < 4; ++n) {
      const int col = tn0 + wc + n * 16 + (l & 15);
      const float bv = bias[col];
#pragma unroll
      for (int r = 0; r < 4; ++r) {
        const int rowg = tm0 + wr + m * 16 + (l >> 4) * 4 + r;
        float v = acc[m][n][r] + bv;
        if (EPI == 0) {
          const int head = col / 384;
          const int rem = col - head * 384;
          const int which = rem >> 7;
          const int d = rem & 127;
          const unsigned short bv16 = f2bf(v);
          if (which == 0)
            q_bf[(long long)(head * SEQL + rowg) * HDIM + d] = bv16;
          else if (which == 1)
            k_bf[(long long)(head * SEQL + rowg) * HDIM + d] = bv16;
          else
            v_t[(long long)(head * HDIM + d) * SEQL + rowg] = bv16;
        } else {
          const long long idx = (long long)rowg * N + col;
          outf[idx] = v + residual[idx];
        }
      }
    }
  }
}

// Flash attention, alibi + causal, swapped-operand in-register softmax.
// Block: one head x 64 q rows; 4 waves x 16 rows; KV tiles of 64.
// sacc[n] = mfma(K-frag, Q-frag) -> lane holds S[kv=n*16+(l>>4)*4+r][q=l&15]:
// lane owns ONE q-row -> local reduce + shfl_xor(16,32); scalar mrun/lrun.
// P -> PV B-operand in registers (cvt_pk pairs + 8 shfl/kk, mapping verified
// per lane group). PV: oacc[n2] = mfma(V^T-frag, P-frag) = O^T fragments;
// transposed through reused Ks slice at the end. LDS 40KB, no Ps buffer.
__global__ __launch_bounds__(256) void attn_fwd(
    const unsigned short* __restrict__ q_bf, const unsigned short* __restrict__ k_bf,
    const unsigned short* __restrict__ v_t, const float* __restrict__ alibi,
    unsigned short* __restrict__ ctx_bf) {
  __shared__ unsigned short Ks[64 * 128];   // 16 KiB (rows = kv, 256B/row)
  __shared__ unsigned short Vs[128 * 64];   // 16 KiB (rows = d, 128B/row)
  __shared__ float Al[SEQL];                // 8 KiB  (alibi*log2e)

  const int tid = threadIdx.x;
  const int l = tid & 63;
  const int w = tid >> 6;
  const int q = l & 15;        // this lane's q-row (local)
  const int g = l >> 4;        // lane group 0..3

  const float LOG2E = 1.4426950408889634f;

  const int b = blockIdx.x;
  const int i_ = b >> 3;
  const int h = (b & 7) * 4 + (i_ & 3);
  const int qtile = 31 - (i_ >> 2);
  const int qw = qtile * 64 + w * 16;
  const int qrow = qw + q;     // this lane's global q row
  const int ntiles = qtile + 1;

  for (int i = tid; i < SEQL; i += 256) Al[i] = alibi[h * SEQL + i] * LOG2E;

  // Q fragments (B-operand): lane holds col q, k-slice kk*32+(l>>4)*8.
  bf16x8 qf[4];
  {
    const unsigned short* qp =
        &q_bf[(long long)(h * SEQL + qw + q) * HDIM + g * 8];
#pragma unroll
    for (int kk = 0; kk < 4; ++kk) qf[kk] = *(const bf16x8*)(qp + kk * 32);
  }

  f32x4 oacc[8] = {};          // O^T: oacc[n2][r] = O^T[d=n2*16+g*4+r][q]
  float mrun = -__builtin_inff();
  float lrun = 0.f;
  const float inv_norm2 = 0.08838834764831845f * 1.4426950408889634f;

  const int kR = l >> 4, kC = l & 15;
  const int vR = l >> 3, vC = (l & 7) ^ vR;

  for (int t = 0; t < ntiles; ++t) {
    const int kv0 = t * 64;
    __syncthreads();
#pragma unroll
    for (int i = 0; i < 4; ++i) {
      const int krow = w * 16 + i * 4 + kR;
      const int ksrc = kC ^ ((i & 1) * 4 + kR);
      gload_lds16(&k_bf[(long long)(h * SEQL + kv0 + krow) * HDIM + ksrc * 8],
                  (char*)Ks + (w * 4 + i) * 1024);
      const int vrow = w * 32 + i * 8 + vR;
      gload_lds16(&v_t[(long long)(h * HDIM + vrow) * SEQL + kv0 + vC * 8],
                  (char*)Vs + (w * 4 + i) * 1024);
    }
    __syncthreads();

    if (kv0 <= qw + 15) {      // wave-uniform live guard
      // Swapped QK^T: sacc[n][r] = S[kv = kv0+n*16+g*4+r][q]
      f32x4 sacc[4] = {};
#pragma unroll
      for (int kk = 0; kk < 4; ++kk) {
        const int colb = kk * 64 + g * 16;
#pragma unroll
        for (int n = 0; n < 4; ++n) {
          const int row = n * 16 + q;
          bf16x8 kf = *(const bf16x8*)((char*)Ks + row * 256 + (colb ^ ((row & 7) << 4)));
          sacc[n] = __builtin_amdgcn_mfma_f32_16x16x32_bf16(kf, qf[kk], sacc[n], 0, 0, 0);
        }
      }

      // alibi (exp2 domain) + scale + causal mask; p[n][r] in registers.
      float p[4][4];
      float m0 = -__builtin_inff();
#pragma unroll
      for (int n = 0; n < 4; ++n) {
        const f32x4 alv = *(const f32x4*)(Al + kv0 + n * 16 + g * 4);
#pragma unroll
        for (int r = 0; r < 4; ++r) {
          const int kv = kv0 + n * 16 + g * 4 + r;
          float v = alv[r] + inv_norm2 * sacc[n][r];
          v = (kv > qrow) ? -__builtin_inff() : v;
          p[n][r] = v;
          m0 = fmaxf(m0, v);
        }
      }
      // row max: lanes {q, q+16, q+32, q+48} hold row q.
      m0 = fmaxf(m0, __shfl_xor(m0, 16, 64));
      m0 = fmaxf(m0, __shfl_xor(m0, 32, 64));
      if (__ballot(m0 > mrun + 11.0f)) {   // defer-max, headroom 2^11
        const float mnew = fmaxf(mrun, m0);
        const float scale = exp2f(mrun - mnew);
        mrun = mnew;
        lrun *= scale;
#pragma unroll
        for (int n2 = 0; n2 < 8; ++n2)
#pragma unroll
          for (int r = 0; r < 4; ++r) oacc[n2][r] *= scale;
      }
      float p0 = 0.f;
#pragma unroll
      for (int n = 0; n < 4; ++n)
#pragma unroll
        for (int r = 0; r < 4; ++r) {
          const float pv = exp2f(p[n][r] - mrun);
          p[n][r] = pv;
          p0 += pv;
        }
      p0 += __shfl_xor(p0, 16, 64);
      p0 += __shfl_xor(p0, 32, 64);
      lrun += p0;

      // Repack P to PV B-operand: lane needs kv-slot j=0..7 -> kv32 = g*8+j.
      // src lane s0 = q + 32*(g&1) (j=0..3), s2 = s0+16 (j=4..7);
      // pk-even (n even) for g<2, pk-odd (n odd) for g>=2.
      bf16x8 pb[2];
#pragma unroll
      for (int kk2 = 0; kk2 < 2; ++kk2) {
        const int n0 = 2 * kk2;
        const unsigned pk0 = cvtpk(p[n0][0], p[n0][1]);
        const unsigned pk1 = cvtpk(p[n0][2], p[n0][3]);
        const unsigned pk2 = cvtpk(p[n0 + 1][0], p[n0 + 1][1]);
        const unsigned pk3 = cvtpk(p[n0 + 1][2], p[n0 + 1][3]);
        const int s0 = q + 32 * (g & 1);
        const int s2 = s0 + 16;
        const unsigned a0 = __shfl((int)pk0, s0, 64), b0 = __shfl((int)pk2, s0, 64);
        const unsigned a1 = __shfl((int)pk1, s0, 64), b1 = __shfl((int)pk3, s0, 64);
        const unsigned a2 = __shfl((int)pk0, s2, 64), b2 = __shfl((int)pk2, s2, 64);
        const unsigned a3 = __shfl((int)pk1, s2, 64), b3 = __shfl((int)pk3, s2, 64);
        const bool lo = (g < 2);
        u32x4 wv;
        wv[0] = lo ? a0 : b0; wv[1] = lo ? a1 : b1;
        wv[2] = lo ? a2 : b2; wv[3] = lo ? a3 : b3;
        pb[kk2] = __builtin_bit_cast(bf16x8, wv);
      }

      // PV: oacc[n2] = mfma(V^T-frag, P-frag): O^T[d][q].
#pragma unroll
      for (int n2 = 0; n2 < 8; ++n2) {
#pragma unroll
        for (int kk2 = 0; kk2 < 2; ++kk2) {
          const int row = n2 * 16 + q;
          const int colb = kk2 * 64 + g * 16;
          bf16x8 vf = *(const bf16x8*)((char*)Vs + row * 128 + (colb ^ ((row & 7) << 4)));
          oacc[n2] = __builtin_amdgcn_mfma_f32_16x16x32_bf16(vf, pb[kk2], oacc[n2], 0, 0, 0);
        }
      }
    }
  }

  // Epilogue: transpose O^T -> O via per-wave LDS slice (reuse Ks).
  __syncthreads();  // all waves done reading Ks/Vs
  {
    char* scr = (char*)Ks + w * 4096;  // [16 q][128 d] bf16, swizzled rows
    const float rdiv = 1.0f / lrun;
#pragma unroll
    for (int n2 = 0; n2 < 8; ++n2)
#pragma unroll
      for (int r = 0; r < 4; ++r) {
        const int d = n2 * 16 + g * 4 + r;
        *(unsigned short*)(scr + ((q * 256 + d * 2) ^ ((q & 7) << 4))) =
            f2bf(oacc[n2][r] * rdiv);
      }
    __threadfence_block();
    const int q2 = l >> 2;             // row this lane writes out
#pragma unroll
    for (int i = 0; i < 4; ++i) {
      const int chunk = (l & 3) + i * 4;
      u16x8 v = *(const u16x8*)(scr + ((q2 * 256 + chunk * 16) ^ ((q2 & 7) << 4)));
      *(u16x8*)&ctx_bf[(long long)(qw + q2) * HIDN + h * HDIM + chunk * 8] = v;
    }
  }
}

extern "C" void kernel_launch(void* const* d_in, const int* in_sizes, int n_in,
                              void* d_out, int out_size, void* d_ws, size_t ws_size,
                              hipStream_t stream) {
  const float* hidden = (const float*)d_in[0];
  const float* residual = (const float*)d_in[1];
  const float* alibi = (const float*)d_in[2];
  // d_in[3]: attention_mask (bool) — causal mask computed analytically
  const float* Wqkv = (const float*)d_in[4];
  const float* bqkv = (const float*)d_in[5];
  const float* Wd = (const float*)d_in[6];
  const float* bd = (const float*)d_in[7];
  float* out = (float*)d_out;

  char* ws = (char*)d_ws;
  const size_t MB16 = 16777216;
  unsigned short* q_bf = (unsigned short*)(ws);
  unsigned short* k_bf = (unsigned short*)(ws + MB16);
  unsigned short* v_t = (unsigned short*)(ws + 2 * MB16);
  unsigned short* hid_bf = (unsigned short*)(ws + 3 * MB16);
  unsigned short* wqkv_bf = (unsigned short*)(ws + 4 * MB16);  // 96 MiB
  unsigned short* wd_bf = (unsigned short*)(ws + 4 * MB16);    // reuse after QKV GEMM
  unsigned short* ctx_bf = (unsigned short*)(ws + 4 * MB16 + 33554432);

  // 1. convert inputs to bf16
  cvt_f32_bf16<<<4096, 256, 0, stream>>>(hidden, hid_bf, (long long)SEQL * HIDN);
  cvt_f32_bf16<<<24576, 256, 0, stream>>>(Wqkv, wqkv_bf, (long long)H3 * HIDN);

  // 2. QKV projection (128^2, XCD-chunked) with interleaved-scatter epilogue
  gemm_nt<0><<<(SEQL / 128) * (H3 / 128), 256, 0, stream>>>(
      hid_bf, wqkv_bf, SEQL, H3, HIDN, bqkv, nullptr, nullptr, q_bf, k_bf, v_t);

  // 3. convert Wd (reuses Wqkv region — stream-ordered after QKV GEMM)
  cvt_f32_bf16<<<8192, 256, 0, stream>>>(Wd, wd_bf, (long long)HIDN * HIDN);

  // 4. flash attention (alibi + causal), swapped-QK^T in-register softmax
  attn_fwd<<<NHEAD * (SEQL / 64), 256, 0, stream>>>(q_bf, k_bf, v_t, alibi, ctx_bf);

  // 5. output projection + bias + residual (fp32 out)
  gemm_nt<1><<<(SEQL / 128) * (HIDN / 128), 256, 0, stream>>>(
      ctx_bf, wd_bf, SEQL, HIDN, HIDN, bd, residual, out, nullptr, nullptr, nullptr);
}